// Round 7
// baseline (2259.462 us; speedup 1.0000x reference)
//
#include <hip/hip_runtime.h>

// ---------------------------------------------------------------------------
// BidirectionalMLP equilibrium relaxation on MI355X.
// s1,s2: [256,4096], s3: [256,10].  25 steps of:
//   s1' = clip(0.5*s1 + CC + 0.25*(r2@bw1))          CC = 0.25*(rx@fw0), const
//   s2' = clip(0.5*s2 + 0.25*(r1@fw1) + 0.25*(r3@bw2))
//   s3' = clip((0.5-beta)*s3 + 0.5*(r2@fw2) + beta*y)
// bf16 MFMA 16x16x32, fp32 accum. Weights transposed once to [N][K] bf16.
// Round 10: A off the LDS path. Round-6 showed the 64x64/2-block structure
// sits AT its LDS-port floor (96KB/pair through one port = ~1460cy observed
// ~= floor; MFMA floor only 310cy). Now A-fragments load global->register
// directly (A is 2MB, L2-resident; 16x64B segments per frag instr), LDS
// carries only B (48KB/pair ~600-730cy) while A's 32KB/pair rides the
// separate TCP port concurrently. Stages are now 2 gload_lds (B only);
// A-loads (4/iter) issue after each gate; steady gate vmcnt(6) = newer
// stage(2)+A(4), tail vmcnt(4). Compiler's per-register waits cover A deps
// without draining stages. Everything else identical to round 6 (2 blk/CU,
// ring-4 B + s3 ring, named ping-pong reg sets, same epilogues/rounding).
// ---------------------------------------------------------------------------

typedef __attribute__((ext_vector_type(4))) float f32x4;
typedef __attribute__((ext_vector_type(8))) short short8;

__device__ __forceinline__ unsigned short f2b(float f) {
    union { float f; unsigned int u; } v;
    v.f = f;
    unsigned int r = v.u + 0x7fffu + ((v.u >> 16) & 1u);
    return (unsigned short)(r >> 16);
}

__device__ __forceinline__ float clamp01(float v) {
    return fminf(fmaxf(v, 0.0f), 1.0f);
}

__device__ __forceinline__ void async16(const unsigned short* g, unsigned short* l) {
    __builtin_amdgcn_global_load_lds(
        (__attribute__((address_space(1))) void*)g,
        (__attribute__((address_space(3))) void*)l,
        16, 0, 0);
}

// B-tile LDS: rows of 8 chunks (16B each); chunk position within a row is
// XOR-swizzled by (row&7) applied to the GLOBAL source k-chunk so the LDS
// destination stays linear (global_load_lds requirement) while ds_read_b128
// fragment reads spread banks.
__device__ __forceinline__ short8 frag_ld(const unsigned short* lds, int row, int ksel) {
    int chunk = (row << 3) + (ksel ^ (row & 7));
    return *reinterpret_cast<const short8*>(lds + (chunk << 3));
}

#define MFMA_BF16 __builtin_amdgcn_mfma_f32_16x16x32_bf16

// Core: C[64x64] tile of A[256,K] @ B^T[N,K] at (M0,N0). 256 threads, 4 waves
// 2x2 (each wave 32x32). BK=64. B: 4-slot LDS ring, stage depth 3, counted
// vmcnt gates. A: direct global->register, ping-pong sets, loaded right
// after each barrier (compiler tracks the register deps precisely).
// Steady half-iteration (current set X, next set Y, step k):
//   vmcnt(6)    -- retire stage k+1 (in flight: stage k+2 [2] + A(k) [4])
//   s_barrier   -- B slot k+1 valid for all waves
//   ALOAD(Y,k+1); PREB(Y,k+1)  -- global A-frags + ds_read B-frags
//   STAGE(k+3)  -- 2 gload_lds into slot (k-1)&3 (last read 2 barriers ago)
//   MMA(X)      -- 8 MFMA (+2 s3); A/B regs ready since previous half
// Tail gate vmcnt(4) (no stage k+2 in flight; A still outstanding).
// s3blk stages are 3 ops -> gates over-wait by <=1 op on 4/512 blocks: safe.
__device__ __forceinline__ void gemm_core(
    const unsigned short* __restrict__ Ag,
    const unsigned short* __restrict__ Bg,
    int K, int M0, int N0,
    unsigned short (*ldsB)[64 * 64],
    unsigned short (*ldsS)[16 * 64],
    f32x4* acc,
    const unsigned short* __restrict__ FW2T, f32x4* acc2,
    bool s3blk, bool doS3,
    int tid)
{
    const int lane = tid & 63;
    const int wave = tid >> 6;
    const int wm = (wave >> 1) << 5;   // 0 / 32
    const int wn = (wave & 1) << 5;    // 0 / 32
    const int fr = lane & 15;
    const int fq = lane >> 4;
    const int nks = K >> 6;

    // Per-lane A base: row M0+wm+fr, k-chunk fq. A-frag (ki, mf) is at
    // base + mf*16*K + ki*32 + k0  (16B load, 64B-contiguous per 4 lanes).
    const unsigned short* Abase = Ag + (size_t)(M0 + wm + fr) * K + (fq << 3);

    auto STAGE = [&](int ks) {
        const int slot = ks & 3;
        const int k0 = ks << 6;
        unsigned short* lB = ldsB[slot];
#pragma unroll
        for (int r = 0; r < 2; ++r) {  // B: 64 rows x 8 chunks = 512
            int cb = (r << 8) + tid;
            int row = cb >> 3, kcs = cb & 7;
            int kc = kcs ^ (row & 7);
            async16(Bg + (size_t)(N0 + row) * K + k0 + (kc << 3), lB + (cb << 3));
        }
        if (s3blk && tid < 128) {      // FW2T: 16 rows x 8 chunks = 128
            int row = tid >> 3, kcs = tid & 7;
            int kc = kcs ^ (row & 7);
            async16(FW2T + (size_t)row * 4096 + k0 + (kc << 3),
                    ldsS[slot] + (tid << 3));
        }
    };

    auto ALOAD = [&](short8 (&A)[2][2], int ks) {
        const unsigned short* p = Abase + (size_t)(ks << 6);
        A[0][0] = *reinterpret_cast<const short8*>(p);
        A[1][0] = *reinterpret_cast<const short8*>(p + 32);
        A[0][1] = *reinterpret_cast<const short8*>(p + (size_t)16 * K);
        A[1][1] = *reinterpret_cast<const short8*>(p + (size_t)16 * K + 32);
    };

    auto PREB = [&](short8 (&B)[2][2], short8 (&S)[2], int ks) {
        const int slot = ks & 3;
        const unsigned short* lB = ldsB[slot];
#pragma unroll
        for (int ki = 0; ki < 2; ++ki) {
            const int ksel = (ki << 2) + fq;
            B[ki][0] = frag_ld(lB, wn + fr, ksel);
            B[ki][1] = frag_ld(lB, wn + 16 + fr, ksel);
            if (doS3) S[ki] = frag_ld(ldsS[slot], fr, ksel);
        }
    };

    auto MMA = [&](short8 (&A)[2][2], short8 (&B)[2][2], short8 (&S)[2]) {
#pragma unroll
        for (int ki = 0; ki < 2; ++ki) {
            acc[0] = MFMA_BF16(A[ki][0], B[ki][0], acc[0], 0, 0, 0);
            acc[1] = MFMA_BF16(A[ki][0], B[ki][1], acc[1], 0, 0, 0);
            acc[2] = MFMA_BF16(A[ki][1], B[ki][0], acc[2], 0, 0, 0);
            acc[3] = MFMA_BF16(A[ki][1], B[ki][1], acc[3], 0, 0, 0);
            if (doS3) {
                acc2[0] = MFMA_BF16(A[ki][0], S[ki], acc2[0], 0, 0, 0);
                acc2[1] = MFMA_BF16(A[ki][1], S[ki], acc2[1], 0, 0, 0);
            }
        }
    };

    short8 A0[2][2], B0[2][2], S0[2];
    short8 A1[2][2], B1[2][2], S1[2];

    STAGE(0); STAGE(1); STAGE(2);      // 3 B-tiles in flight (6 ops, s3: 9)

    asm volatile("s_waitcnt vmcnt(4)" ::: "memory");   // retire stage 0
    __builtin_amdgcn_s_barrier();
    asm volatile("" ::: "memory");
    ALOAD(A0, 0);
    PREB(B0, S0, 0);

    for (int ks = 0; ks < nks; ks += 2) {
        // ---- even half: cur = set0, prefetch set1(ks+1) ----
        if (ks + 1 < nks) {
            if (ks + 2 < nks) asm volatile("s_waitcnt vmcnt(6)" ::: "memory");
            else              asm volatile("s_waitcnt vmcnt(4)" ::: "memory");
            __builtin_amdgcn_s_barrier();
            asm volatile("" ::: "memory");
            ALOAD(A1, ks + 1);
            PREB(B1, S1, ks + 1);
        }
        if (ks + 3 < nks) STAGE(ks + 3);
        MMA(A0, B0, S0);
        // ---- odd half: cur = set1, prefetch set0(ks+2) ----
        if (ks + 2 < nks) {
            if (ks + 3 < nks) asm volatile("s_waitcnt vmcnt(6)" ::: "memory");
            else              asm volatile("s_waitcnt vmcnt(4)" ::: "memory");
            __builtin_amdgcn_s_barrier();
            asm volatile("" ::: "memory");
            ALOAD(A0, ks + 2);
            PREB(B0, S0, ks + 2);
        }
        if (ks + 4 < nks) STAGE(ks + 4);
        MMA(A1, B1, S1);
    }
}

// One relaxation step. Grid = 512 blocks: [0,256) GEMM1 (-> s1, s3),
// [256,512) GEMM2 (-> s2). 64x64 tiles over [256, 4096]. nt is the fast
// block index so panel-mates (b, b+64, ...) land on the same XCD (64%8==0).
__global__ __launch_bounds__(256) void step_kernel(
    const unsigned short* __restrict__ R2old,
    const unsigned short* __restrict__ R1old,
    const float* __restrict__ S1old, const float* __restrict__ S2old,
    const float* __restrict__ S3old,
    float* __restrict__ S1new, float* __restrict__ S2new, float* __restrict__ S3new,
    unsigned short* __restrict__ R1new, unsigned short* __restrict__ R2new,
    const unsigned short* __restrict__ B1T, const unsigned short* __restrict__ B2T,
    const unsigned short* __restrict__ FW2T,
    const float* __restrict__ CC, const float* __restrict__ bw2,
    const float* __restrict__ y, float beta)
{
    __shared__ __align__(16) unsigned short ldsB[4][64 * 64];
    __shared__ __align__(16) unsigned short ldsS[4][16 * 64];
    const int tid = threadIdx.x;
    const int b = blockIdx.x;
    const bool g1 = (b < 256);
    int mt, nt;
    const unsigned short *A, *B;
    if (g1) { mt = b >> 6; nt = b & 63; A = R2old; B = B1T; }
    else    { int bb = b - 256; mt = bb >> 6; nt = bb & 63; A = R1old; B = B2T; }
    const int M0 = mt << 6, N0 = nt << 6;

    const int lane = tid & 63;
    const int wave = tid >> 6;
    const int wm = (wave >> 1) << 5;
    const int wn = (wave & 1) << 5;
    const int fr = lane & 15;
    const int fq = lane >> 4;
    const bool s3blk = g1 && (nt == 0);          // block-uniform
    const bool doS3 = s3blk && (wn == 0);        // wave-uniform

    f32x4 acc[4], acc2[2];
    f32x4 zero = {0.f, 0.f, 0.f, 0.f};
#pragma unroll
    for (int i = 0; i < 4; ++i) acc[i] = zero;
    acc2[0] = zero; acc2[1] = zero;

    gemm_core(A, B, 4096, M0, N0, ldsB, ldsS, acc,
              FW2T, acc2, s3blk, doS3, tid);

    if (g1) {
#pragma unroll
        for (int i = 0; i < 4; ++i) {
            int im = i >> 1, in_ = i & 1;
            int n = N0 + wn + (in_ << 4) + fr;
#pragma unroll
            for (int rr = 0; rr < 4; ++rr) {
                int m = M0 + wm + (im << 4) + (fq << 2) + rr;
                size_t o = (size_t)m * 4096 + n;
                float v = 0.5f * S1old[o] + CC[o] + 0.25f * acc[i][rr];
                v = clamp01(v);
                S1new[o] = v;
                R1new[o] = f2b(v);
            }
        }
        if (doS3 && fr < 10) {
#pragma unroll
            for (int im = 0; im < 2; ++im) {
#pragma unroll
                for (int rr = 0; rr < 4; ++rr) {
                    int m = M0 + wm + (im << 4) + (fq << 2) + rr;
                    float s3 = S3old[m * 10 + fr];
                    float v = (0.5f - beta) * s3 + 0.5f * acc2[im][rr]
                              + beta * y[m * 10 + fr];
                    v = clamp01(v);
                    S3new[m * 10 + fr] = v;
                }
            }
        }
    } else {
#pragma unroll
        for (int i = 0; i < 4; ++i) {
            int im = i >> 1, in_ = i & 1;
            int n = N0 + wn + (in_ << 4) + fr;
#pragma unroll
            for (int rr = 0; rr < 4; ++rr) {
                int m = M0 + wm + (im << 4) + (fq << 2) + rr;
                size_t o = (size_t)m * 4096 + n;
                float dot = 0.f;
#pragma unroll
                for (int j = 0; j < 10; ++j)
                    dot += S3old[m * 10 + j] * bw2[j * 4096 + n];
                float v = 0.5f * S2old[o] + 0.25f * acc[i][rr] + 0.25f * dot;
                v = clamp01(v);
                S2new[o] = v;
                R2new[o] = f2b(v);
            }
        }
    }
}

// CC = 0.25*(rx @ fw0). A = RX [256,1024] bf16, B = FW0T [4096,1024] bf16.
// 64x64 tiles -> 256 blocks.
__global__ __launch_bounds__(256) void c1_kernel(
    const unsigned short* __restrict__ RX,
    const unsigned short* __restrict__ FW0T,
    float* __restrict__ CC)
{
    __shared__ __align__(16) unsigned short ldsB[4][64 * 64];
    __shared__ __align__(16) unsigned short ldsS[4][16 * 64];
    const int tid = threadIdx.x;
    const int b = blockIdx.x;
    const int mt = b >> 6, nt = b & 63;
    const int M0 = mt << 6, N0 = nt << 6;

    f32x4 acc[4], acc2[2];
    f32x4 zero = {0.f, 0.f, 0.f, 0.f};
#pragma unroll
    for (int i = 0; i < 4; ++i) acc[i] = zero;
    acc2[0] = zero; acc2[1] = zero;

    gemm_core(RX, FW0T, 1024, M0, N0, ldsB, ldsS, acc,
              nullptr, acc2, false, false, tid);

    const int lane = tid & 63;
    const int wave = tid >> 6;
    const int wm = (wave >> 1) << 5;
    const int wn = (wave & 1) << 5;
    const int fr = lane & 15;
    const int fq = lane >> 4;
#pragma unroll
    for (int i = 0; i < 4; ++i) {
        int im = i >> 1, in_ = i & 1;
        int n = N0 + wn + (in_ << 4) + fr;
#pragma unroll
        for (int rr = 0; rr < 4; ++rr) {
            int m = M0 + wm + (im << 4) + (fq << 2) + rr;
            CC[(size_t)m * 4096 + n] = 0.25f * acc[i][rr];
        }
    }
}

// src [R][C] fp32 row-major -> dst [C][R] bf16 (dst row stride = R).
__global__ __launch_bounds__(256) void transpose_cvt(
    const float* __restrict__ src, unsigned short* __restrict__ dst,
    int R, int C)
{
    __shared__ float t[32][33];
    const int c0 = blockIdx.x << 5, r0 = blockIdx.y << 5;
    const int tx = threadIdx.x & 31, ty = threadIdx.x >> 5;   // ty: 0..7
#pragma unroll
    for (int i = 0; i < 32; i += 8)
        t[ty + i][tx] = src[(size_t)(r0 + ty + i) * C + (c0 + tx)];
    __syncthreads();
#pragma unroll
    for (int i = 0; i < 32; i += 8)
        dst[(size_t)(c0 + ty + i) * R + (r0 + tx)] = f2b(t[tx][ty + i]);
}

// FW2T fill, rx convert, zero-init of ping buffers.
__global__ __launch_bounds__(256) void misc_init(
    const float* __restrict__ x, const float* __restrict__ fw2,
    unsigned short* __restrict__ FW2T, unsigned short* __restrict__ RX,
    float* __restrict__ S1, float* __restrict__ S2, float* __restrict__ S3,
    unsigned short* __restrict__ R1, unsigned short* __restrict__ R2)
{
    const int stride = gridDim.x * blockDim.x;
    const int t0 = blockIdx.x * blockDim.x + threadIdx.x;
    for (int i = t0; i < 16 * 4096; i += stride) {      // FW2T[n][k] = fw2[k][n]
        int n = i >> 12, k = i & 4095;
        FW2T[i] = (n < 10) ? f2b(fw2[k * 10 + n]) : (unsigned short)0;
    }
    for (int i = t0; i < 256 * 1024; i += stride)
        RX[i] = f2b(clamp01(x[i]));
    for (int i = t0; i < 256 * 4096; i += stride) {
        S1[i] = 0.f; S2[i] = 0.f; R1[i] = 0; R2[i] = 0;
    }
    for (int i = t0; i < 2560; i += stride) S3[i] = 0.f;
}

__global__ __launch_bounds__(256) void pack_kernel(
    const float* __restrict__ S1, const float* __restrict__ S2,
    const float* __restrict__ S3, float* __restrict__ out)
{
    const int stride = gridDim.x * blockDim.x;
    for (int i = blockIdx.x * blockDim.x + threadIdx.x; i < 256 * 8202; i += stride) {
        int m = i / 8202, c = i - m * 8202;
        float v;
        if (c < 4096)       v = S1[(size_t)m * 4096 + c];
        else if (c < 8192)  v = S2[(size_t)m * 4096 + (c - 4096)];
        else                v = S3[m * 10 + (c - 8192)];
        out[i] = v;
    }
}

extern "C" void kernel_launch(void* const* d_in, const int* in_sizes, int n_in,
                              void* d_out, int out_size, void* d_ws, size_t ws_size,
                              hipStream_t stream) {
    const float* x   = (const float*)d_in[0];
    const float* fw0 = (const float*)d_in[1];
    const float* fw1 = (const float*)d_in[2];
    const float* fw2 = (const float*)d_in[3];
    // d_in[4] = bw0 : unused by the reference
    const float* bw1 = (const float*)d_in[5];
    const float* bw2 = (const float*)d_in[6];
    const float* y   = (const float*)d_in[7];

    char* ws = (char*)d_ws;
    // workspace layout (bytes)
    unsigned short* B1T  = (unsigned short*)(ws + 0);          // 4096x4096 bf16
    unsigned short* B2T  = (unsigned short*)(ws + 33554432);   // 4096x4096 bf16
    unsigned short* FW0T = (unsigned short*)(ws + 67108864);   // 4096x1024 bf16
    unsigned short* FW2T = (unsigned short*)(ws + 75497472);   // 16x4096 bf16
    unsigned short* RX   = (unsigned short*)(ws + 75628544);   // 256x1024 bf16
    float*          CC   = (float*)(ws + 76152832);            // 256x4096 f32
    float*          S1f  = (float*)(ws + 80347136);            // 2 x 256x4096 f32
    float*          S2f  = (float*)(ws + 88735744);            // 2 x 256x4096 f32
    float*          S3f  = (float*)(ws + 97124352);            // 2 x 256x10 f32
    unsigned short* R1   = (unsigned short*)(ws + 97144832);   // 2 x 256x4096 bf16
    unsigned short* R2   = (unsigned short*)(ws + 101339136);  // 2 x 256x4096 bf16
    // total ~105.6 MB

    const size_t SB = 256 * 4096;  // state buffer elems
    dim3 blk(256);

    transpose_cvt<<<dim3(128, 128), blk, 0, stream>>>(bw1, B1T, 4096, 4096);
    transpose_cvt<<<dim3(128, 128), blk, 0, stream>>>(fw1, B2T, 4096, 4096);
    transpose_cvt<<<dim3(128, 32),  blk, 0, stream>>>(fw0, FW0T, 1024, 4096);
    misc_init<<<512, blk, 0, stream>>>(x, fw2, FW2T, RX,
                                       S1f, S2f, S3f, R1, R2);
    c1_kernel<<<256, blk, 0, stream>>>(RX, FW0T, CC);

    for (int t = 0; t < 25; ++t) {
        const int o = t & 1, nw = o ^ 1;
        const float beta = (t < 20) ? 0.0f : 0.5f;
        step_kernel<<<512, blk, 0, stream>>>(
            R2 + o * SB, R1 + o * SB,
            S1f + o * SB, S2f + o * SB, S3f + o * 2560,
            S1f + nw * SB, S2f + nw * SB, S3f + nw * 2560,
            R1 + nw * SB, R2 + nw * SB,
            B1T, B2T, FW2T, CC, bw2, y, beta);
    }

    pack_kernel<<<2048, blk, 0, stream>>>(S1f + SB, S2f + SB, S3f + 2560,
                                          (float*)d_out);
}